// Round 4
// baseline (611.074 us; speedup 1.0000x reference)
//
#include <hip/hip_runtime.h>
#include <hip/hip_bf16.h>
#include <math.h>

typedef __attribute__((ext_vector_type(8))) short short8b;
typedef __attribute__((ext_vector_type(4))) float f32x4;

#define BSZ 32
#define NHW 196
#define M_ROWS 6272
#define MPAD 6400
#define CDIM 512
#define MSZ 16384
#define NCLS 100
#define ALPHA 0.1f

#define NTILES 128            // 16384/128 key tiles
#define GRID_MFMA 3200        // 25 m-tiles x 128 n-tiles
#define BUFSZ 49152           // Qh 16K | Ql 16K | Kh 8K | Kl 8K

// ---------------- per-location sum-of-squares partials (c-split x4) ----------------
__global__ __launch_bounds__(256) void k_invnorm4(const float* __restrict__ q,
                                                  float* __restrict__ ssq4) {
    int b = blockIdx.x, cc = blockIdx.y, n = threadIdx.x;
    if (n >= NHW) return;
    const float* base = q + ((size_t)b * CDIM + cc * 128) * NHW + n;
    float ss = 0.f;
#pragma unroll 8
    for (int c = 0; c < 128; ++c) { float v = base[(size_t)c * NHW]; ss = fmaf(v, v, ss); }
    ssq4[(size_t)(b * NHW + n) * 4 + cc] = ss;
}

// ---------------- hi/lo bf16 decomposition ----------------
// Layout: X[kb][row][cc], kb = c>>5, cc = c&31  (elements, ushort)
__global__ __launch_bounds__(256) void k_decomp_q(
    const float* __restrict__ Q, const float* __restrict__ ssq4,
    unsigned short* __restrict__ qhi, unsigned short* __restrict__ qlo)
{
    __shared__ unsigned short lh[32][65], ll[32][65];
    const int t = threadIdx.x;
    const int rb = blockIdx.x % 100, kb = blockIdx.x / 100;
    const int r0 = rb * 64, c0 = kb * 32;
    const int cin = t >> 6, rin = t & 63;
    const int r = r0 + rin;
    float iv = 0.f;
    if (r < M_ROWS) {
        const float4 s4 = *reinterpret_cast<const float4*>(ssq4 + (size_t)r * 4);
        iv = 1.f / fmaxf(sqrtf((s4.x + s4.y) + (s4.z + s4.w)), 1e-12f);
    }
    const int b = r / NHW, n = r - b * NHW;
#pragma unroll
    for (int ci = 0; ci < 8; ++ci) {
        int cl = ci * 4 + cin;
        float x = 0.f;
        if (r < M_ROWS) x = Q[((size_t)(b * CDIM + (c0 + cl))) * NHW + n] * iv;
        __hip_bfloat16 h = __float2bfloat16(x);
        float hf = __bfloat162float(h);
        __hip_bfloat16 lo = __float2bfloat16(x - hf);
        lh[cl][rin] = *(unsigned short*)&h;
        ll[cl][rin] = *(unsigned short*)&lo;
    }
    __syncthreads();
    const int r2 = t >> 2, seg = t & 3;
    short8b vh, vl;
#pragma unroll
    for (int i = 0; i < 8; ++i) {
        vh[i] = (short)lh[seg * 8 + i][r2];
        vl[i] = (short)ll[seg * 8 + i][r2];
    }
    size_t off = ((size_t)kb * MPAD + r0 + r2) * 32 + seg * 8;
    *(short8b*)(qhi + off) = vh;
    *(short8b*)(qlo + off) = vl;
}

__global__ __launch_bounds__(256) void k_decomp_k(
    const float* __restrict__ K,
    unsigned short* __restrict__ khi, unsigned short* __restrict__ klo)
{
    int tid = blockIdx.x * 256 + threadIdx.x;
    int c4 = tid & 127, key = tid >> 7;
    int c = c4 << 2;
    const float4 v = *reinterpret_cast<const float4*>(K + (size_t)key * CDIM + c);
    float xs[4] = {v.x, v.y, v.z, v.w};
    unsigned short hs[4], ls[4];
#pragma unroll
    for (int i = 0; i < 4; ++i) {
        __hip_bfloat16 h = __float2bfloat16(xs[i]);
        float hf = __bfloat162float(h);
        __hip_bfloat16 lo = __float2bfloat16(xs[i] - hf);
        hs[i] = *(unsigned short*)&h; ls[i] = *(unsigned short*)&lo;
    }
    size_t off = ((size_t)(c >> 5) * MSZ + key) * 32 + (c & 31);
    ushort4 H; H.x = hs[0]; H.y = hs[1]; H.z = hs[2]; H.w = hs[3];
    ushort4 L; L.x = ls[0]; L.y = ls[1]; L.z = ls[2]; L.w = ls[3];
    *reinterpret_cast<ushort4*>(khi + off) = H;
    *reinterpret_cast<ushort4*>(klo + off) = L;
}

// ---------------- split-bf16 MFMA GEMM, 3-buffer counted-vmcnt pipeline ----------------
__device__ __forceinline__ void gload16(const void* g, void* lds) {
    __builtin_amdgcn_global_load_lds((const __attribute__((address_space(1))) void*)g,
                                     (__attribute__((address_space(3))) void*)lds,
                                     16, 0, 0);
}

__global__ __launch_bounds__(512, 2) void k_mfma(
    const unsigned short* __restrict__ qhi, const unsigned short* __restrict__ qlo,
    const unsigned short* __restrict__ khi, const unsigned short* __restrict__ klo,
    const int* __restrict__ mvals, const int* __restrict__ tgt,
    float* __restrict__ pmax, int* __restrict__ pidx,
    float* __restrict__ ppos, float* __restrict__ pneg)
{
    __shared__ char smem[3 * BUFSZ];   // 144 KB: 3 bufs of [Qh16K|Ql16K|Kh8K|Kl8K]

    const int tid = threadIdx.x;
    const int w = tid >> 6, l = tid & 63;

    // XCD-aware bijective swizzle (3200 % 8 == 0), nt-fast for A-panel L2 reuse
    const int s = ((blockIdx.x & 7) * 400) + (blockIdx.x >> 3);
    const int mt = s >> 7, nt = s & 127;
    const int r0 = mt * 256, n0 = nt * 128;

    // staging decode (LDS dest linear = wave base + lane*16; source pre-swizzled)
    const int srow = l >> 2;                               // 0..15
    const int sg8 = (((l & 3) ^ ((l >> 3) & 3)) << 3);     // slot ^= (row>>1)&3, elements
    // fragment-read decode (inverse swizzle)
    const int fr = l & 15;
    const int abyte = (fr << 6) + ((((l >> 4) ^ ((l >> 1) & 3))) << 4);

    const int wm = w >> 2, wn = w & 3;
    const int arow0 = wm * 128;       // 8 m-fragments of 16
    const int bcol0 = wn * 32;        // 2 n-fragments of 16

    f32x4 acc[8][2];
    const f32x4 zero4 = {0.f, 0.f, 0.f, 0.f};
#pragma unroll
    for (int m = 0; m < 8; ++m)
#pragma unroll
        for (int n = 0; n < 2; ++n) acc[m][n] = zero4;

    // per-wave staging constants
    const int qdst = w * 2048;        // Qh/Ql rows [32w,32w+32)
    const int kdst = w * 1024;        // Kh/Kl rows [16w,16w+16)

#define STAGE(BN, KT)                                                          \
    {                                                                          \
        char* bn_ = (BN);                                                      \
        const size_t qb_ = ((size_t)(KT) * MPAD + r0) * 32;                    \
        const size_t kb_ = ((size_t)(KT) * MSZ + n0) * 32;                     \
        _Pragma("unroll")                                                      \
        for (int j = 0; j < 2; ++j) {                                          \
            const int rr = w * 32 + j * 16 + srow;                             \
            const size_t qo = qb_ + (size_t)rr * 32 + sg8;                     \
            gload16(qhi + qo, bn_ + 0     + qdst + j * 1024);                  \
            gload16(qlo + qo, bn_ + 16384 + qdst + j * 1024);                  \
        }                                                                      \
        const int rk = w * 16 + srow;                                          \
        const size_t ko_ = kb_ + (size_t)rk * 32 + sg8;                        \
        gload16(khi + ko_, bn_ + 32768 + kdst);                                \
        gload16(klo + ko_, bn_ + 40960 + kdst);                                \
    }

    // ---- prologue: stage ks=0 and ks=1 ----
    STAGE(smem + 0 * BUFSZ, 0);
    STAGE(smem + 1 * BUFSZ, 1);
    asm volatile("s_waitcnt vmcnt(6)" ::: "memory");   // ks0's 6 landed
    __builtin_amdgcn_s_barrier();

    for (int ks = 0; ks < 16; ++ks) {
        const char* bc = smem + (ks % 3) * BUFSZ;
        if (ks < 14) {
            STAGE(smem + ((ks + 2) % 3) * BUFSZ, ks + 2);   // 2-step lookahead
        }

        // ---- B-frags (Kh/Kl) ----
        short8b bh[2], bl[2];
#pragma unroll
        for (int n = 0; n < 2; ++n) {
            const int rb = (bcol0 + n * 16) << 6;
            bh[n] = *(const short8b*)(bc + 32768 + rb + abyte);
            bl[n] = *(const short8b*)(bc + 40960 + rb + abyte);
        }

        // ---- 2 phases of 4 m-fragments each ----
#pragma unroll
        for (int p = 0; p < 2; ++p) {
            short8b ah[4], al[4];
#pragma unroll
            for (int i = 0; i < 4; ++i) {
                const int ra = (arow0 + (4 * p + i) * 16) << 6;
                ah[i] = *(const short8b*)(bc + 0     + ra + abyte);
                al[i] = *(const short8b*)(bc + 16384 + ra + abyte);
            }
            __builtin_amdgcn_s_barrier();
            __builtin_amdgcn_s_setprio(1);
#pragma unroll
            for (int i = 0; i < 4; ++i) {
                const int m = 4 * p + i;
#pragma unroll
                for (int n = 0; n < 2; ++n) {
                    acc[m][n] = __builtin_amdgcn_mfma_f32_16x16x32_bf16(ah[i], bh[n], acc[m][n], 0, 0, 0);
                    acc[m][n] = __builtin_amdgcn_mfma_f32_16x16x32_bf16(ah[i], bl[n], acc[m][n], 0, 0, 0);
                    acc[m][n] = __builtin_amdgcn_mfma_f32_16x16x32_bf16(al[i], bh[n], acc[m][n], 0, 0, 0);
                }
            }
            __builtin_amdgcn_s_setprio(0);
            __builtin_amdgcn_s_barrier();
        }

        // ---- end of step: wait ks+1's loads only; ks+2's stay in flight ----
        if (ks < 14) { asm volatile("s_waitcnt vmcnt(6)" ::: "memory"); }
        else         { asm volatile("s_waitcnt vmcnt(0)" ::: "memory"); }
        __builtin_amdgcn_s_barrier();
    }
    __syncthreads();

    // ---- epilogue: per-row {max,argmax,pos,neg} over this 128-key tile ----
    float* wpmax = (float*)smem;               // [4][256]
    int*   wpidx = (int*)(smem + 4096);
    float* wppos = (float*)(smem + 8192);
    float* wpneg = (float*)(smem + 12288);
    int*   mv_s  = (int*)(smem + 16384);       // [128]
    if (tid < NTILES) mv_s[tid] = mvals[n0 + tid];
    __syncthreads();

#pragma unroll
    for (int m = 0; m < 8; ++m) {
#pragma unroll
        for (int rg = 0; rg < 4; ++rg) {
            const int rloc = arow0 + m * 16 + ((l >> 4) << 2) + rg;
            const int rglob = r0 + rloc;
            int samp = rglob / NHW; samp = samp > 31 ? 31 : samp;
            const int tg = tgt[samp];
            float vmax = -INFINITY; int vidx = 0;
            float p = -INFINITY, ng = -INFINITY;
#pragma unroll
            for (int n = 0; n < 2; ++n) {          // ascending cols -> first-max kept
                const int cl = bcol0 + n * 16 + fr;
                const float v = acc[m][n][rg];
                if (v > vmax) { vmax = v; vidx = n0 + cl; }
                const bool corr = (mv_s[cl] == tg);
                p  = fmaxf(p,  corr ? v : 0.f);    // mask-by-multiply semantics
                ng = fmaxf(ng, corr ? 0.f : v);
            }
#pragma unroll
            for (int off = 1; off < 16; off <<= 1) {
                const float om = __shfl_xor(vmax, off, 16);
                const int   oi = __shfl_xor(vidx, off, 16);
                const float op = __shfl_xor(p, off, 16);
                const float on = __shfl_xor(ng, off, 16);
                if (om > vmax || (om == vmax && oi < vidx)) { vmax = om; vidx = oi; }
                p = fmaxf(p, op); ng = fmaxf(ng, on);
            }
            if (fr == 0) {
                const int o = wn * 256 + rloc;
                wpmax[o] = vmax; wpidx[o] = vidx;
                wppos[o] = p;    wpneg[o] = ng;
            }
        }
    }
    __syncthreads();
    if (tid < 256) {
        float vmax = -INFINITY; int vidx = 0; float p = -INFINITY, ng = -INFINITY;
#pragma unroll
        for (int q_ = 0; q_ < 4; ++q_) {           // ascending wn = ascending cols
            const int o = q_ * 256 + tid;
            const float m_ = wpmax[o]; const int i_ = wpidx[o];
            if (m_ > vmax || (m_ == vmax && i_ < vidx)) { vmax = m_; vidx = i_; }
            p = fmaxf(p, wppos[o]); ng = fmaxf(ng, wpneg[o]);
        }
        const size_t o = (size_t)(r0 + tid) * NTILES + nt;
        pmax[o] = vmax; pidx[o] = vidx; ppos[o] = p; pneg[o] = ng;
    }
#undef STAGE
}

// ---------------- fp32 fallback GEMM (round-1, verified) ----------------
#define BM 128
#define BN 128
#define BK 16
#define LDA (BM + 4)
#define LDB (BN + 4)

__global__ __launch_bounds__(256) void k_invnorm(const float* __restrict__ q,
                                                 float* __restrict__ invq) {
    int b = blockIdx.x, n = threadIdx.x;
    if (n >= NHW) return;
    const float* base = q + (size_t)b * CDIM * NHW + n;
    float ss = 0.f;
#pragma unroll 4
    for (int c = 0; c < CDIM; ++c) { float v = base[(size_t)c * NHW]; ss = fmaf(v, v, ss); }
    invq[b * NHW + n] = 1.f / fmaxf(sqrtf(ss), 1e-12f);
}

__global__ __launch_bounds__(256) void k_gemm_reduce(
    const float* __restrict__ Q, const float* __restrict__ Kz,
    const int* __restrict__ mvals, const int* __restrict__ tgt,
    const float* __restrict__ invq,
    float* __restrict__ pmax, int* __restrict__ pidx,
    float* __restrict__ ppos, float* __restrict__ pneg)
{
    __shared__ float As[BK][LDA];
    __shared__ float Bs[BK][LDB];
    __shared__ float run_max[BM];
    __shared__ int   run_idx[BM];
    __shared__ float run_pos[BM];
    __shared__ float run_neg[BM];
    __shared__ int   mv_s[BN];
    __shared__ int   tgt_s[BM];
    __shared__ float inv_s[BM];

    const int t = threadIdx.x;
    const int rt = blockIdx.x % 49;
    const int chunk = blockIdx.x / 49;
    const int r0 = rt * BM;

    if (t < BM) {
        run_max[t] = -INFINITY; run_idx[t] = 0;
        run_pos[t] = -INFINITY; run_neg[t] = -INFINITY;
        int row = r0 + t;
        tgt_s[t] = tgt[row / NHW];
        inv_s[t] = invq[row];
    }
    const int ty = t >> 4, tx = t & 15;
    __syncthreads();

    for (int tile = 0; tile < 8; ++tile) {
        const int key0 = chunk * 1024 + tile * BN;
        if (t < BN) mv_s[t] = mvals[key0 + t];
        float acc[8][8];
#pragma unroll
        for (int i = 0; i < 8; ++i)
#pragma unroll
            for (int j = 0; j < 8; ++j) acc[i][j] = 0.f;

        for (int ks = 0; ks < 32; ++ks) {
            const int c0 = ks * BK;
            __syncthreads();
#pragma unroll
            for (int it = 0; it < 2; ++it) {
                int i = t + it * 256;
                int k = i >> 5;
                int r4 = (i & 31) << 2;
                int row = r0 + r4;
                int b = row / NHW;
                int n = row - b * NHW;
                const float4 v = *reinterpret_cast<const float4*>(
                    Q + ((size_t)(b * CDIM + c0 + k)) * NHW + n);
                float4 w;
                w.x = v.x * inv_s[r4 + 0]; w.y = v.y * inv_s[r4 + 1];
                w.z = v.z * inv_s[r4 + 2]; w.w = v.w * inv_s[r4 + 3];
                *reinterpret_cast<float4*>(&As[k][r4]) = w;
            }
#pragma unroll
            for (int it = 0; it < 2; ++it) {
                int i = t + it * 256;
                int key = i >> 2;
                int cc = (i & 3) << 2;
                const float4 v = *reinterpret_cast<const float4*>(
                    Kz + (size_t)(key0 + key) * CDIM + c0 + cc);
                Bs[cc + 0][key] = v.x; Bs[cc + 1][key] = v.y;
                Bs[cc + 2][key] = v.z; Bs[cc + 3][key] = v.w;
            }
            __syncthreads();
#pragma unroll
            for (int k = 0; k < BK; ++k) {
                float4 a0 = *reinterpret_cast<const float4*>(&As[k][4 * ty]);
                float4 a1 = *reinterpret_cast<const float4*>(&As[k][64 + 4 * ty]);
                float4 b0 = *reinterpret_cast<const float4*>(&Bs[k][4 * tx]);
                float4 b1 = *reinterpret_cast<const float4*>(&Bs[k][64 + 4 * tx]);
                float a[8] = {a0.x, a0.y, a0.z, a0.w, a1.x, a1.y, a1.z, a1.w};
                float bb[8] = {b0.x, b0.y, b0.z, b0.w, b1.x, b1.y, b1.z, b1.w};
#pragma unroll
                for (int i = 0; i < 8; ++i)
#pragma unroll
                    for (int j = 0; j < 8; ++j)
                        acc[i][j] = fmaf(a[i], bb[j], acc[i][j]);
            }
        }
#pragma unroll
        for (int i = 0; i < 8; ++i) {
            int rl = (i < 4) ? (4 * ty + i) : (64 + 4 * ty + i - 4);
            int tgti = tgt_s[rl];
            float vmax = -INFINITY; int vidx = 0;
            float p = -INFINITY, ng = -INFINITY;
#pragma unroll
            for (int j = 0; j < 8; ++j) {
                int cl = (j < 4) ? (4 * tx + j) : (64 + 4 * tx + j - 4);
                float v = acc[i][j];
                int gk = key0 + cl;
                if (v > vmax) { vmax = v; vidx = gk; }
                bool corr = (mv_s[cl] == tgti);
                p  = fmaxf(p,  corr ? v : 0.f);
                ng = fmaxf(ng, corr ? 0.f : v);
            }
#pragma unroll
            for (int off = 1; off < 16; off <<= 1) {
                float om = __shfl_xor(vmax, off, 16);
                int   oi = __shfl_xor(vidx, off, 16);
                float op = __shfl_xor(p,    off, 16);
                float on = __shfl_xor(ng,   off, 16);
                if (om > vmax || (om == vmax && oi < vidx)) { vmax = om; vidx = oi; }
                p = fmaxf(p, op); ng = fmaxf(ng, on);
            }
            if (tx == 0) {
                if (vmax > run_max[rl]) { run_max[rl] = vmax; run_idx[rl] = vidx; }
                run_pos[rl] = fmaxf(run_pos[rl], p);
                run_neg[rl] = fmaxf(run_neg[rl], ng);
            }
        }
        __syncthreads();
    }
    if (t < BM) {
        int row = r0 + t;
        size_t o = (size_t)row * 16 + chunk;
        pmax[o] = run_max[t]; pidx[o] = run_idx[t];
        ppos[o] = run_pos[t]; pneg[o] = run_neg[t];
    }
}

// ---------------- merge + vote + loss ----------------
__global__ __launch_bounds__(256) void k_merge(
    const int* __restrict__ mvals, const int* __restrict__ tgt,
    const float* __restrict__ pmax, const int* __restrict__ pidx,
    const float* __restrict__ ppos, const float* __restrict__ pneg,
    float* __restrict__ out, float* __restrict__ means, int nch)
{
    __shared__ int counts[NCLS];
    __shared__ float perloc[256];
    __shared__ int haspos;
    const int b = blockIdx.x, t = threadIdx.x;
    if (t == 0) haspos = 0;
    if (t < NCLS) counts[t] = 0;
    perloc[t] = 0.f;
    __syncthreads();
    const int tg = tgt[b];
    int found = 0;
    for (int i = t; i < MSZ; i += 256) found |= (mvals[i] == tg) ? 1 : 0;
    if (found) atomicOr(&haspos, 1);
    __syncthreads();
    if (t < NHW) {
        int row = b * NHW + t;
        float vmax = -INFINITY; int vidx = 0;
        float p = -INFINITY, ng = -INFINITY;
        for (int c = 0; c < nch; ++c) {
            size_t o = (size_t)row * nch + c;
            float m = pmax[o]; int i_ = pidx[o];
            if (m > vmax || (m == vmax && i_ < vidx)) { vmax = m; vidx = i_; }
            p = fmaxf(p, ppos[o]); ng = fmaxf(ng, pneg[o]);
        }
        atomicAdd(&counts[mvals[vidx]], 1);
        perloc[t] = haspos ? fmaxf(ng - p + ALPHA, 0.f)
                           : fmaxf(ng + ALPHA, 0.f);
    }
    __syncthreads();
    for (int s = 128; s > 0; s >>= 1) {
        if (t < s) perloc[t] += perloc[t + s];
        __syncthreads();
    }
    if (t == 0) {
        int bestc = 0, bestn = counts[0];
        for (int c = 1; c < NCLS; ++c)
            if (counts[c] > bestn) { bestn = counts[c]; bestc = c; }
        out[b] = (float)bestc;
        means[b] = perloc[0] / (float)NHW;
    }
}

__global__ __launch_bounds__(64) void k_final(const float* __restrict__ means,
                                              float* __restrict__ out) {
    if (threadIdx.x == 0) {
        float s = 0.f;
        for (int b = 0; b < BSZ; ++b) s += means[b];
        out[BSZ] = s;
    }
}

extern "C" void kernel_launch(void* const* d_in, const int* in_sizes, int n_in,
                              void* d_out, int out_size, void* d_ws, size_t ws_size,
                              hipStream_t stream) {
    const float* q  = (const float*)d_in[0];
    const int*   tg = (const int*)d_in[1];
    const float* mk = (const float*)d_in[2];
    const int*   mv = (const int*)d_in[3];
    float* out = (float*)d_out;

    unsigned short* khi = (unsigned short*)d_ws;
    unsigned short* klo = khi + (size_t)MSZ * CDIM;
    unsigned short* qhi = klo + (size_t)MSZ * CDIM;
    unsigned short* qlo = qhi + (size_t)MPAD * CDIM;
    float* ssq4  = (float*)(qlo + (size_t)MPAD * CDIM);
    float* pmax  = ssq4 + (size_t)M_ROWS * 4;
    float* ppos  = pmax + (size_t)MPAD * NTILES;
    float* pneg  = ppos + (size_t)MPAD * NTILES;
    int*   pidx  = (int*)(pneg + (size_t)MPAD * NTILES);
    float* means = (float*)(pidx + (size_t)MPAD * NTILES);
    size_t need = (size_t)((char*)(means + BSZ) - (char*)d_ws);

    if (ws_size >= need) {
        k_invnorm4<<<dim3(BSZ, 4), 256, 0, stream>>>(q, ssq4);
        k_decomp_q<<<1600, 256, 0, stream>>>(q, ssq4, qhi, qlo);
        k_decomp_k<<<(MSZ * 128) / 256, 256, 0, stream>>>(mk, khi, klo);
        k_mfma<<<GRID_MFMA, 512, 0, stream>>>(qhi, qlo, khi, klo, mv, tg,
                                              pmax, pidx, ppos, pneg);
        k_merge<<<BSZ, 256, 0, stream>>>(mv, tg, pmax, pidx, ppos, pneg, out, means, NTILES);
        k_final<<<1, 64, 0, stream>>>(means, out);
    } else {
        float* invq0  = (float*)d_ws;
        float* pmax0  = invq0 + M_ROWS;
        float* ppos0  = pmax0 + (size_t)M_ROWS * 16;
        float* pneg0  = ppos0 + (size_t)M_ROWS * 16;
        int*   pidx0  = (int*)(pneg0 + (size_t)M_ROWS * 16);
        float* means0 = (float*)(pidx0 + (size_t)M_ROWS * 16);
        k_invnorm<<<BSZ, 256, 0, stream>>>(q, invq0);
        k_gemm_reduce<<<49 * 16, 256, 0, stream>>>(q, mk, mv, tg, invq0,
                                                   pmax0, pidx0, ppos0, pneg0);
        k_merge<<<BSZ, 256, 0, stream>>>(mv, tg, pmax0, pidx0, ppos0, pneg0, out, means0, 16);
        k_final<<<1, 64, 0, stream>>>(means0, out);
    }
}

// Round 5
// 433.799 us; speedup vs baseline: 1.4087x; 1.4087x over previous
//
#include <hip/hip_runtime.h>
#include <hip/hip_bf16.h>
#include <math.h>

typedef __attribute__((ext_vector_type(8))) short short8b;
typedef __attribute__((ext_vector_type(4))) float f32x4;

#define BSZ 32
#define NHW 196
#define M_ROWS 6272
#define MPAD 6400
#define CDIM 512
#define MSZ 16384
#define NCLS 100
#define ALPHA 0.1f

// ---------------- per-location sum-of-squares partials (c-split x4) ----------------
__global__ __launch_bounds__(256) void k_invnorm4(const float* __restrict__ q,
                                                  float* __restrict__ ssq4) {
    int b = blockIdx.x, cc = blockIdx.y, n = threadIdx.x;
    if (n >= NHW) return;
    const float* base = q + ((size_t)b * CDIM + cc * 128) * NHW + n;
    float ss = 0.f;
#pragma unroll 8
    for (int c = 0; c < 128; ++c) { float v = base[(size_t)c * NHW]; ss = fmaf(v, v, ss); }
    ssq4[(size_t)(b * NHW + n) * 4 + cc] = ss;
}

// ---------------- hi/lo bf16 decomposition ----------------
// Layout: X[kb][row][cc], kb = c>>5, cc = c&31  (elements, ushort)
__global__ __launch_bounds__(256) void k_decomp_q(
    const float* __restrict__ Q, const float* __restrict__ ssq4,
    unsigned short* __restrict__ qhi, unsigned short* __restrict__ qlo)
{
    __shared__ unsigned short lh[32][65], ll[32][65];
    const int t = threadIdx.x;
    const int rb = blockIdx.x % 100, kb = blockIdx.x / 100;
    const int r0 = rb * 64, c0 = kb * 32;
    const int cin = t >> 6, rin = t & 63;
    const int r = r0 + rin;
    float iv = 0.f;
    if (r < M_ROWS) {
        const float4 s4 = *reinterpret_cast<const float4*>(ssq4 + (size_t)r * 4);
        iv = 1.f / fmaxf(sqrtf((s4.x + s4.y) + (s4.z + s4.w)), 1e-12f);
    }
    const int b = r / NHW, n = r - b * NHW;
#pragma unroll
    for (int ci = 0; ci < 8; ++ci) {
        int cl = ci * 4 + cin;
        float x = 0.f;
        if (r < M_ROWS) x = Q[((size_t)(b * CDIM + (c0 + cl))) * NHW + n] * iv;
        __hip_bfloat16 h = __float2bfloat16(x);
        float hf = __bfloat162float(h);
        __hip_bfloat16 lo = __float2bfloat16(x - hf);
        lh[cl][rin] = *(unsigned short*)&h;
        ll[cl][rin] = *(unsigned short*)&lo;
    }
    __syncthreads();
    const int r2 = t >> 2, seg = t & 3;
    short8b vh, vl;
#pragma unroll
    for (int i = 0; i < 8; ++i) {
        vh[i] = (short)lh[seg * 8 + i][r2];
        vl[i] = (short)ll[seg * 8 + i][r2];
    }
    size_t off = ((size_t)kb * MPAD + r0 + r2) * 32 + seg * 8;
    *(short8b*)(qhi + off) = vh;
    *(short8b*)(qlo + off) = vl;
}

__global__ __launch_bounds__(256) void k_decomp_k(
    const float* __restrict__ K,
    unsigned short* __restrict__ khi, unsigned short* __restrict__ klo)
{
    int tid = blockIdx.x * 256 + threadIdx.x;
    int c4 = tid & 127, key = tid >> 7;
    int c = c4 << 2;
    const float4 v = *reinterpret_cast<const float4*>(K + (size_t)key * CDIM + c);
    float xs[4] = {v.x, v.y, v.z, v.w};
    unsigned short hs[4], ls[4];
#pragma unroll
    for (int i = 0; i < 4; ++i) {
        __hip_bfloat16 h = __float2bfloat16(xs[i]);
        float hf = __bfloat162float(h);
        __hip_bfloat16 lo = __float2bfloat16(xs[i] - hf);
        hs[i] = *(unsigned short*)&h; ls[i] = *(unsigned short*)&lo;
    }
    size_t off = ((size_t)(c >> 5) * MSZ + key) * 32 + (c & 31);
    ushort4 H; H.x = hs[0]; H.y = hs[1]; H.z = hs[2]; H.w = hs[3];
    ushort4 L; L.x = ls[0]; L.y = ls[1]; L.z = ls[2]; L.w = ls[3];
    *reinterpret_cast<ushort4*>(khi + off) = H;
    *reinterpret_cast<ushort4*>(klo + off) = L;
}

// ---------------- split-bf16 MFMA GEMM, double-buffered phase schedule ----------------
// Mapping: each XCD owns 8 n-tiles (2048 keys, ~4.2MB hi+lo) -> B-slice ~L2-resident;
// mt-outer within XCD so concurrent blocks co-read one A-panel.
__device__ __forceinline__ void gload16(const void* g, void* lds) {
    __builtin_amdgcn_global_load_lds((const __attribute__((address_space(1))) void*)g,
                                     (__attribute__((address_space(3))) void*)lds,
                                     16, 0, 0);
}

__global__ __launch_bounds__(512, 2) void k_mfma(
    const unsigned short* __restrict__ qhi, const unsigned short* __restrict__ qlo,
    const unsigned short* __restrict__ khi, const unsigned short* __restrict__ klo,
    const int* __restrict__ mvals, const int* __restrict__ tgt,
    float* __restrict__ pmax, int* __restrict__ pidx,
    float* __restrict__ ppos, float* __restrict__ pneg)
{
    __shared__ char smem[2][65536];   // [dbuf][Qh16K|Ql16K|Kh16K|Kl16K]

    const int tid = threadIdx.x;
    const int w = tid >> 6, l = tid & 63;

    // XCD key-slice mapping (1600 blocks, 8 XCDs x 200)
    const int orig = blockIdx.x;
    const int xcd = orig & 7;
    const int idx = orig >> 3;            // 0..199
    const int mt = idx >> 3;              // 0..24 (outer)
    const int nt = (xcd << 3) | (idx & 7);// 0..63 (this XCD's 8 n-tiles, inner)
    const int r0 = mt * 256, n0 = nt * 256;

    // staging decode: LDS dest linear (wave base + lane*16); source pre-swizzled
    const int srow = l >> 2;
    const int sg8 = (((l & 3) ^ ((l >> 3) & 3)) << 3);
    // fragment read decode (inverse swizzle on ds_read address)
    const int fr = l & 15;
    const int abyte = (fr << 6) + ((((l >> 4) ^ ((l >> 1) & 3))) << 4);

    const int wm = w >> 2, wn = w & 3;
    const int arow0 = wm * 128, bcol0 = wn * 64;
    const int ldsw = w * 2048;

    f32x4 acc[8][4];
    const f32x4 zero4 = {0.f, 0.f, 0.f, 0.f};
#pragma unroll
    for (int m = 0; m < 8; ++m)
#pragma unroll
        for (int n = 0; n < 4; ++n) acc[m][n] = zero4;

    // ---- prologue: stage ks=0 into buffer 0 ----
    {
        const size_t qb0 = (size_t)r0 * 32;
        const size_t kb0 = (size_t)n0 * 32;
#pragma unroll
        for (int j = 0; j < 2; ++j) {
            const int rr = w * 32 + j * 16 + srow;
            const size_t qo = qb0 + (size_t)rr * 32 + sg8;
            const size_t ko = kb0 + (size_t)rr * 32 + sg8;
            gload16(qhi + qo, smem[0] + 0     + ldsw + j * 1024);
            gload16(qlo + qo, smem[0] + 16384 + ldsw + j * 1024);
            gload16(khi + ko, smem[0] + 32768 + ldsw + j * 1024);
            gload16(klo + ko, smem[0] + 49152 + ldsw + j * 1024);
        }
    }
    __syncthreads();

    int cur = 0;
    for (int ks = 0; ks < 16; ++ks) {
        const char* bc = smem[cur];
        char* bn = smem[cur ^ 1];
        const bool pf = (ks < 15);
        const size_t qb = ((size_t)(ks + 1) * MPAD + r0) * 32;
        const size_t kb_ = ((size_t)(ks + 1) * MSZ + n0) * 32;

        // ---- B-frag phase ----
        short8b bh[4], bl[4];
#pragma unroll
        for (int n = 0; n < 4; ++n) {
            const int rb = (bcol0 + n * 16) << 6;
            bh[n] = *(const short8b*)(bc + 32768 + rb + abyte);
            bl[n] = *(const short8b*)(bc + 49152 + rb + abyte);
        }
        __builtin_amdgcn_s_barrier();

        // ---- 4 m-pair phases ----
#pragma unroll
        for (int p = 0; p < 4; ++p) {
            const int m0 = 2 * p, m1 = 2 * p + 1;
            const int ra0 = (arow0 + m0 * 16) << 6;
            const int ra1 = (arow0 + m1 * 16) << 6;
            short8b ah0 = *(const short8b*)(bc + 0     + ra0 + abyte);
            short8b al0 = *(const short8b*)(bc + 16384 + ra0 + abyte);
            short8b ah1 = *(const short8b*)(bc + 0     + ra1 + abyte);
            short8b al1 = *(const short8b*)(bc + 16384 + ra1 + abyte);
            if (pf) {
                const unsigned short* sp = (p == 0) ? qhi : (p == 1) ? qlo
                                          : (p == 2) ? khi : klo;
                const size_t sb = (p < 2) ? qb : kb_;
#pragma unroll
                for (int j = 0; j < 2; ++j) {
                    const int rr = w * 32 + j * 16 + srow;
                    gload16(sp + sb + (size_t)rr * 32 + sg8,
                            bn + p * 16384 + ldsw + j * 1024);
                }
            }
            __builtin_amdgcn_s_barrier();
            __builtin_amdgcn_s_setprio(1);
#pragma unroll
            for (int n = 0; n < 4; ++n) {
                acc[m0][n] = __builtin_amdgcn_mfma_f32_16x16x32_bf16(ah0, bh[n], acc[m0][n], 0, 0, 0);
                acc[m0][n] = __builtin_amdgcn_mfma_f32_16x16x32_bf16(ah0, bl[n], acc[m0][n], 0, 0, 0);
                acc[m0][n] = __builtin_amdgcn_mfma_f32_16x16x32_bf16(al0, bh[n], acc[m0][n], 0, 0, 0);
                acc[m1][n] = __builtin_amdgcn_mfma_f32_16x16x32_bf16(ah1, bh[n], acc[m1][n], 0, 0, 0);
                acc[m1][n] = __builtin_amdgcn_mfma_f32_16x16x32_bf16(ah1, bl[n], acc[m1][n], 0, 0, 0);
                acc[m1][n] = __builtin_amdgcn_mfma_f32_16x16x32_bf16(al1, bh[n], acc[m1][n], 0, 0, 0);
            }
            __builtin_amdgcn_s_setprio(0);
            __builtin_amdgcn_s_barrier();
        }
        __syncthreads();   // vmcnt(0) drain: prefetched tile landed; flip buffers
        cur ^= 1;
    }
    __syncthreads();

    // ---- epilogue: per-row {max,argmax,pos,neg} over this 256-key tile ----
    float* wpmax = (float*)smem[0];               // [4][256]
    int*   wpidx = (int*)(smem[0] + 4096);
    float* wppos = (float*)(smem[0] + 8192);
    float* wpneg = (float*)(smem[0] + 12288);
    int*   mv_s  = (int*)(smem[0] + 16384);       // [256]
    if (tid < 256) mv_s[tid] = mvals[n0 + tid];
    __syncthreads();

#pragma unroll
    for (int m = 0; m < 8; ++m) {
#pragma unroll
        for (int rg = 0; rg < 4; ++rg) {
            const int rloc = arow0 + m * 16 + ((l >> 4) << 2) + rg;
            const int rglob = r0 + rloc;
            int samp = rglob / NHW; samp = samp > 31 ? 31 : samp;
            const int tg = tgt[samp];
            float vmax = -INFINITY; int vidx = 0;
            float p = -INFINITY, ng = -INFINITY;
#pragma unroll
            for (int n = 0; n < 4; ++n) {          // ascending cols -> first-max kept
                const int cl = bcol0 + n * 16 + fr;
                const float v = acc[m][n][rg];
                if (v > vmax) { vmax = v; vidx = n0 + cl; }
                const bool corr = (mv_s[cl] == tg);
                p  = fmaxf(p,  corr ? v : 0.f);    // mask-by-multiply semantics
                ng = fmaxf(ng, corr ? 0.f : v);
            }
#pragma unroll
            for (int off = 1; off < 16; off <<= 1) {
                const float om = __shfl_xor(vmax, off, 16);
                const int   oi = __shfl_xor(vidx, off, 16);
                const float op = __shfl_xor(p, off, 16);
                const float on = __shfl_xor(ng, off, 16);
                if (om > vmax || (om == vmax && oi < vidx)) { vmax = om; vidx = oi; }
                p = fmaxf(p, op); ng = fmaxf(ng, on);
            }
            if (fr == 0) {
                const int o = wn * 256 + rloc;
                wpmax[o] = vmax; wpidx[o] = vidx;
                wppos[o] = p;    wpneg[o] = ng;
            }
        }
    }
    __syncthreads();
    if (tid < 256) {
        float vmax = -INFINITY; int vidx = 0; float p = -INFINITY, ng = -INFINITY;
#pragma unroll
        for (int q_ = 0; q_ < 4; ++q_) {           // ascending wn = ascending cols
            const int o = q_ * 256 + tid;
            const float m_ = wpmax[o]; const int i_ = wpidx[o];
            if (m_ > vmax || (m_ == vmax && i_ < vidx)) { vmax = m_; vidx = i_; }
            p = fmaxf(p, wppos[o]); ng = fmaxf(ng, wpneg[o]);
        }
        const size_t o = (size_t)(r0 + tid) * 64 + nt;
        pmax[o] = vmax; pidx[o] = vidx; ppos[o] = p; pneg[o] = ng;
    }
}

// ---------------- fp32 fallback GEMM (round-1, verified) ----------------
#define BM 128
#define BN 128
#define BK 16
#define LDA (BM + 4)
#define LDB (BN + 4)

__global__ __launch_bounds__(256) void k_invnorm(const float* __restrict__ q,
                                                 float* __restrict__ invq) {
    int b = blockIdx.x, n = threadIdx.x;
    if (n >= NHW) return;
    const float* base = q + (size_t)b * CDIM * NHW + n;
    float ss = 0.f;
#pragma unroll 4
    for (int c = 0; c < CDIM; ++c) { float v = base[(size_t)c * NHW]; ss = fmaf(v, v, ss); }
    invq[b * NHW + n] = 1.f / fmaxf(sqrtf(ss), 1e-12f);
}

__global__ __launch_bounds__(256) void k_gemm_reduce(
    const float* __restrict__ Q, const float* __restrict__ Kz,
    const int* __restrict__ mvals, const int* __restrict__ tgt,
    const float* __restrict__ invq,
    float* __restrict__ pmax, int* __restrict__ pidx,
    float* __restrict__ ppos, float* __restrict__ pneg)
{
    __shared__ float As[BK][LDA];
    __shared__ float Bs[BK][LDB];
    __shared__ float run_max[BM];
    __shared__ int   run_idx[BM];
    __shared__ float run_pos[BM];
    __shared__ float run_neg[BM];
    __shared__ int   mv_s[BN];
    __shared__ int   tgt_s[BM];
    __shared__ float inv_s[BM];

    const int t = threadIdx.x;
    const int rt = blockIdx.x % 49;
    const int chunk = blockIdx.x / 49;
    const int r0 = rt * BM;

    if (t < BM) {
        run_max[t] = -INFINITY; run_idx[t] = 0;
        run_pos[t] = -INFINITY; run_neg[t] = -INFINITY;
        int row = r0 + t;
        tgt_s[t] = tgt[row / NHW];
        inv_s[t] = invq[row];
    }
    const int ty = t >> 4, tx = t & 15;
    __syncthreads();

    for (int tile = 0; tile < 8; ++tile) {
        const int key0 = chunk * 1024 + tile * BN;
        if (t < BN) mv_s[t] = mvals[key0 + t];
        float acc[8][8];
#pragma unroll
        for (int i = 0; i < 8; ++i)
#pragma unroll
            for (int j = 0; j < 8; ++j) acc[i][j] = 0.f;

        for (int ks = 0; ks < 32; ++ks) {
            const int c0 = ks * BK;
            __syncthreads();
#pragma unroll
            for (int it = 0; it < 2; ++it) {
                int i = t + it * 256;
                int k = i >> 5;
                int r4 = (i & 31) << 2;
                int row = r0 + r4;
                int b = row / NHW;
                int n = row - b * NHW;
                const float4 v = *reinterpret_cast<const float4*>(
                    Q + ((size_t)(b * CDIM + c0 + k)) * NHW + n);
                float4 w;
                w.x = v.x * inv_s[r4 + 0]; w.y = v.y * inv_s[r4 + 1];
                w.z = v.z * inv_s[r4 + 2]; w.w = v.w * inv_s[r4 + 3];
                *reinterpret_cast<float4*>(&As[k][r4]) = w;
            }
#pragma unroll
            for (int it = 0; it < 2; ++it) {
                int i = t + it * 256;
                int key = i >> 2;
                int cc = (i & 3) << 2;
                const float4 v = *reinterpret_cast<const float4*>(
                    Kz + (size_t)(key0 + key) * CDIM + c0 + cc);
                Bs[cc + 0][key] = v.x; Bs[cc + 1][key] = v.y;
                Bs[cc + 2][key] = v.z; Bs[cc + 3][key] = v.w;
            }
            __syncthreads();
#pragma unroll
            for (int k = 0; k < BK; ++k) {
                float4 a0 = *reinterpret_cast<const float4*>(&As[k][4 * ty]);
                float4 a1 = *reinterpret_cast<const float4*>(&As[k][64 + 4 * ty]);
                float4 b0 = *reinterpret_cast<const float4*>(&Bs[k][4 * tx]);
                float4 b1 = *reinterpret_cast<const float4*>(&Bs[k][64 + 4 * tx]);
                float a[8] = {a0.x, a0.y, a0.z, a0.w, a1.x, a1.y, a1.z, a1.w};
                float bb[8] = {b0.x, b0.y, b0.z, b0.w, b1.x, b1.y, b1.z, b1.w};
#pragma unroll
                for (int i = 0; i < 8; ++i)
#pragma unroll
                    for (int j = 0; j < 8; ++j)
                        acc[i][j] = fmaf(a[i], bb[j], acc[i][j]);
            }
        }
#pragma unroll
        for (int i = 0; i < 8; ++i) {
            int rl = (i < 4) ? (4 * ty + i) : (64 + 4 * ty + i - 4);
            int tgti = tgt_s[rl];
            float vmax = -INFINITY; int vidx = 0;
            float p = -INFINITY, ng = -INFINITY;
#pragma unroll
            for (int j = 0; j < 8; ++j) {
                int cl = (j < 4) ? (4 * tx + j) : (64 + 4 * tx + j - 4);
                float v = acc[i][j];
                int gk = key0 + cl;
                if (v > vmax) { vmax = v; vidx = gk; }
                bool corr = (mv_s[cl] == tgti);
                p  = fmaxf(p,  corr ? v : 0.f);
                ng = fmaxf(ng, corr ? 0.f : v);
            }
#pragma unroll
            for (int off = 1; off < 16; off <<= 1) {
                float om = __shfl_xor(vmax, off, 16);
                int   oi = __shfl_xor(vidx, off, 16);
                float op = __shfl_xor(p,    off, 16);
                float on = __shfl_xor(ng,   off, 16);
                if (om > vmax || (om == vmax && oi < vidx)) { vmax = om; vidx = oi; }
                p = fmaxf(p, op); ng = fmaxf(ng, on);
            }
            if (tx == 0) {
                if (vmax > run_max[rl]) { run_max[rl] = vmax; run_idx[rl] = vidx; }
                run_pos[rl] = fmaxf(run_pos[rl], p);
                run_neg[rl] = fmaxf(run_neg[rl], ng);
            }
        }
        __syncthreads();
    }
    if (t < BM) {
        int row = r0 + t;
        size_t o = (size_t)row * 16 + chunk;
        pmax[o] = run_max[t]; pidx[o] = run_idx[t];
        ppos[o] = run_pos[t]; pneg[o] = run_neg[t];
    }
}

// ---------------- merge + vote + loss ----------------
__global__ __launch_bounds__(256) void k_merge(
    const int* __restrict__ mvals, const int* __restrict__ tgt,
    const float* __restrict__ pmax, const int* __restrict__ pidx,
    const float* __restrict__ ppos, const float* __restrict__ pneg,
    float* __restrict__ out, float* __restrict__ means, int nch)
{
    __shared__ int counts[NCLS];
    __shared__ float perloc[256];
    __shared__ int haspos;
    const int b = blockIdx.x, t = threadIdx.x;
    if (t == 0) haspos = 0;
    if (t < NCLS) counts[t] = 0;
    perloc[t] = 0.f;
    __syncthreads();
    const int tg = tgt[b];
    int found = 0;
    for (int i = t; i < MSZ; i += 256) found |= (mvals[i] == tg) ? 1 : 0;
    if (found) atomicOr(&haspos, 1);
    __syncthreads();
    if (t < NHW) {
        int row = b * NHW + t;
        float vmax = -INFINITY; int vidx = 0;
        float p = -INFINITY, ng = -INFINITY;
        for (int c = 0; c < nch; ++c) {
            size_t o = (size_t)row * nch + c;
            float m = pmax[o]; int i_ = pidx[o];
            if (m > vmax || (m == vmax && i_ < vidx)) { vmax = m; vidx = i_; }
            p = fmaxf(p, ppos[o]); ng = fmaxf(ng, pneg[o]);
        }
        atomicAdd(&counts[mvals[vidx]], 1);
        perloc[t] = haspos ? fmaxf(ng - p + ALPHA, 0.f)
                           : fmaxf(ng + ALPHA, 0.f);
    }
    __syncthreads();
    for (int s = 128; s > 0; s >>= 1) {
        if (t < s) perloc[t] += perloc[t + s];
        __syncthreads();
    }
    if (t == 0) {
        int bestc = 0, bestn = counts[0];
        for (int c = 1; c < NCLS; ++c)
            if (counts[c] > bestn) { bestn = counts[c]; bestc = c; }
        out[b] = (float)bestc;
        means[b] = perloc[0] / (float)NHW;
    }
}

__global__ __launch_bounds__(64) void k_final(const float* __restrict__ means,
                                              float* __restrict__ out) {
    if (threadIdx.x == 0) {
        float s = 0.f;
        for (int b = 0; b < BSZ; ++b) s += means[b];
        out[BSZ] = s;
    }
}

extern "C" void kernel_launch(void* const* d_in, const int* in_sizes, int n_in,
                              void* d_out, int out_size, void* d_ws, size_t ws_size,
                              hipStream_t stream) {
    const float* q  = (const float*)d_in[0];
    const int*   tg = (const int*)d_in[1];
    const float* mk = (const float*)d_in[2];
    const int*   mv = (const int*)d_in[3];
    float* out = (float*)d_out;

    unsigned short* khi = (unsigned short*)d_ws;
    unsigned short* klo = khi + (size_t)MSZ * CDIM;
    unsigned short* qhi = klo + (size_t)MSZ * CDIM;
    unsigned short* qlo = qhi + (size_t)MPAD * CDIM;
    float* ssq4  = (float*)(qlo + (size_t)MPAD * CDIM);
    float* pmax  = ssq4 + (size_t)M_ROWS * 4;
    float* ppos  = pmax + (size_t)MPAD * 64;
    float* pneg  = ppos + (size_t)MPAD * 64;
    int*   pidx  = (int*)(pneg + (size_t)MPAD * 64);
    float* means = (float*)(pidx + (size_t)MPAD * 64);
    size_t need = (size_t)((char*)(means + BSZ) - (char*)d_ws);

    if (ws_size >= need) {
        k_invnorm4<<<dim3(BSZ, 4), 256, 0, stream>>>(q, ssq4);
        k_decomp_q<<<1600, 256, 0, stream>>>(q, ssq4, qhi, qlo);
        k_decomp_k<<<(MSZ * 128) / 256, 256, 0, stream>>>(mk, khi, klo);
        k_mfma<<<1600, 512, 0, stream>>>(qhi, qlo, khi, klo, mv, tg,
                                         pmax, pidx, ppos, pneg);
        k_merge<<<BSZ, 256, 0, stream>>>(mv, tg, pmax, pidx, ppos, pneg, out, means, 64);
        k_final<<<1, 64, 0, stream>>>(means, out);
    } else {
        float* invq0  = (float*)d_ws;
        float* pmax0  = invq0 + M_ROWS;
        float* ppos0  = pmax0 + (size_t)M_ROWS * 16;
        float* pneg0  = ppos0 + (size_t)M_ROWS * 16;
        int*   pidx0  = (int*)(pneg0 + (size_t)M_ROWS * 16);
        float* means0 = (float*)(pidx0 + (size_t)M_ROWS * 16);
        k_invnorm<<<BSZ, 256, 0, stream>>>(q, invq0);
        k_gemm_reduce<<<49 * 16, 256, 0, stream>>>(q, mk, mv, tg, invq0,
                                                   pmax0, pidx0, ppos0, pneg0);
        k_merge<<<BSZ, 256, 0, stream>>>(mv, tg, pmax0, pidx0, ppos0, pneg0, out, means0, 16);
        k_final<<<1, 64, 0, stream>>>(means0, out);
    }
}